// Round 1
// baseline (92.453 us; speedup 1.0000x reference)
//
#include <hip/hip_runtime.h>
#include <cstddef>

#define BB 4
#define CC 64
#define NN 8192
#define KK 16
#define OO 128

#define SW 136   // LDS row stride (bf16 elems) for W tile: breaks 256B bank aliasing
#define SH 136   // LDS row stride for h tile

typedef __attribute__((ext_vector_type(8))) short bf16x8;
typedef __attribute__((ext_vector_type(4))) float f32x4;

__device__ __forceinline__ unsigned short f2b(float f) {
    unsigned u = __builtin_bit_cast(unsigned, f);
    unsigned r = (u + 0x7fffu + ((u >> 16) & 1u)) >> 16;   // RNE
    return (unsigned short)r;
}

__device__ __forceinline__ float b2f(unsigned short h) {
    unsigned u = ((unsigned)h) << 16;
    return __builtin_bit_cast(float, u);
}

// x: (B, C, N) fp32  ->  xt: (B, N, C) bf16 (as ushort)
__global__ __launch_bounds__(256) void transpose_kernel(
        const float* __restrict__ x, unsigned short* __restrict__ xt) {
    __shared__ float tile[64][65];
    const int b  = blockIdx.y;
    const int n0 = blockIdx.x * 64;
    const int t  = threadIdx.x;
    const int ln = t & 63;
    const int r  = t >> 6;   // wave id 0..3

    const float* xb = x + (size_t)b * CC * NN;
    #pragma unroll
    for (int s = 0; s < 64; s += 4) {
        int c = s + r;
        tile[c][ln] = xb[(size_t)c * NN + n0 + ln];   // coalesced 256B along n
    }
    __syncthreads();
    unsigned short* xtb = xt + ((size_t)b * NN + n0) * CC;
    #pragma unroll
    for (int s = 0; s < 64; s += 4) {
        int n = s + r;
        xtb[n * CC + ln] = f2b(tile[ln][n]);          // coalesced 128B along c
    }
}

// xt: (B, N, 64) bf16; eidx: (2, B, N, 16); W: (128, 128) fp32; bias: (128)
// out: (B, 128, N) fp32
__global__ __launch_bounds__(256) void main_kernel(
        const unsigned short* __restrict__ xt,
        const int*            __restrict__ eidx,
        const float*          __restrict__ W,
        const float*          __restrict__ bias,
        float*                __restrict__ out) {
    __shared__ unsigned short Wl[128 * SW];   // W as bf16, row-major [o][k]
    __shared__ unsigned short hl[64 * SH];    // h as bf16, [node][k], k=2c+{0,1}

    const int t    = threadIdx.x;
    const int lane = t & 63;
    const int w    = t >> 6;            // wave 0..3
    const int b    = blockIdx.y;
    const int n_base = blockIdx.x * 64;

    // ---- stage W (fp32 global -> bf16 LDS) ----
    #pragma unroll
    for (int s = 0; s < 16384; s += 1024) {
        int idx = s + t * 4;
        float4 v = *reinterpret_cast<const float4*>(W + idx);
        int row = idx >> 7;
        int col = idx & 127;
        unsigned short* dst = &Wl[row * SW + col];
        dst[0] = f2b(v.x); dst[1] = f2b(v.y); dst[2] = f2b(v.z); dst[3] = f2b(v.w);
    }

    // ---- phase 1: gather + max-aggregate, 16 nodes per wave ----
    const unsigned short* xtb = xt + (size_t)b * NN * CC;
    const int* e0 = eidx + (size_t)b * NN * KK;            // edge_index[0]
    const int* e1 = e0 + (size_t)BB * NN * KK;             // edge_index[1]
    const int c = lane;                                     // channel 0..63

    for (int nn = 0; nn < 16; nn++) {
        int nl = w * 16 + nn;                               // local node 0..63
        int n_u = __builtin_amdgcn_readfirstlane(n_base + nl);
        const int* p0 = e0 + (size_t)n_u * KK;
        const int* p1 = e1 + (size_t)n_u * KK;

        float xv = b2f(xtb[(size_t)n_u * CC + c]);
        float m = -1e30f;
        #pragma unroll
        for (int k = 0; k < KK; k++) {
            int j = p0[k];                                  // wave-uniform -> s_load
            int i = p1[k];
            float xj = b2f(xtb[(size_t)j * CC + c]);        // coalesced 128B row
            float xi = b2f(xtb[(size_t)i * CC + c]);
            m = fmaxf(m, xj - xi);
        }
        // h[nl][2c] = xv, h[nl][2c+1] = m  (one 4B store per lane)
        unsigned pk = (unsigned)f2b(xv) | ((unsigned)f2b(m) << 16);
        *reinterpret_cast<unsigned*>(&hl[nl * SH + 2 * c]) = pk;
    }
    __syncthreads();

    // ---- phase 2: out[128 x 64] = W[128x128] @ h[128x64], MFMA bf16 ----
    const int quad = lane >> 4;
    const int l15  = lane & 15;
    const int o0w  = w * 32;                                // wave's o-range

    bf16x8 afr[2][4];
    #pragma unroll
    for (int ot = 0; ot < 2; ot++)
        #pragma unroll
        for (int ks = 0; ks < 4; ks++) {
            const unsigned short* ap = &Wl[(o0w + ot * 16 + l15) * SW + ks * 32 + quad * 8];
            afr[ot][ks] = *reinterpret_cast<const bf16x8*>(ap);
        }

    #pragma unroll
    for (int nt = 0; nt < 4; nt++) {
        f32x4 acc0 = {0.f, 0.f, 0.f, 0.f};
        f32x4 acc1 = {0.f, 0.f, 0.f, 0.f};
        #pragma unroll
        for (int ks = 0; ks < 4; ks++) {
            const unsigned short* bp = &hl[(nt * 16 + l15) * SH + ks * 32 + quad * 8];
            bf16x8 bfr = *reinterpret_cast<const bf16x8*>(bp);
            acc0 = __builtin_amdgcn_mfma_f32_16x16x32_bf16(afr[0][ks], bfr, acc0, 0, 0, 0);
            acc1 = __builtin_amdgcn_mfma_f32_16x16x32_bf16(afr[1][ks], bfr, acc1, 0, 0, 0);
        }
        int n_g = n_base + nt * 16 + l15;
        #pragma unroll
        for (int r = 0; r < 4; r++) {
            int o_a = o0w + quad * 4 + r;           // D row = quad*4 + reg
            int o_b = o0w + 16 + quad * 4 + r;
            float va = acc0[r] + bias[o_a];
            float vb = acc1[r] + bias[o_b];
            out[((size_t)b * OO + o_a) * NN + n_g] = fmaxf(va, 0.f);
            out[((size_t)b * OO + o_b) * NN + n_g] = fmaxf(vb, 0.f);
        }
    }
}

extern "C" void kernel_launch(void* const* d_in, const int* in_sizes, int n_in,
                              void* d_out, int out_size, void* d_ws, size_t ws_size,
                              hipStream_t stream) {
    const float* x    = (const float*)d_in[0];
    const int*   eidx = (const int*)d_in[1];
    const float* W    = (const float*)d_in[2];
    const float* bias = (const float*)d_in[3];
    float* out = (float*)d_out;
    unsigned short* xt = (unsigned short*)d_ws;   // (B, N, 64) bf16 = 4 MB

    dim3 blk(256);
    dim3 grid(NN / 64, BB);
    transpose_kernel<<<grid, blk, 0, stream>>>(x, xt);
    main_kernel<<<grid, blk, 0, stream>>>(xt, eidx, W, bias, out);
}

// Round 2
// 83.206 us; speedup vs baseline: 1.1111x; 1.1111x over previous
//
#include <hip/hip_runtime.h>
#include <cstddef>

#define BB 4
#define CC 64
#define NN 8192
#define KK 16
#define OO 128

#define SW 136   // LDS row stride (bf16 elems) for W tile: 272B rows keep 16B align, break bank aliasing
#define SH 136   // LDS row stride for h tile

typedef __attribute__((ext_vector_type(8))) short bf16x8;
typedef __attribute__((ext_vector_type(4))) float f32x4;

__device__ __forceinline__ unsigned short f2b(float f) {
    unsigned u = __builtin_bit_cast(unsigned, f);
    unsigned r = (u + 0x7fffu + ((u >> 16) & 1u)) >> 16;   // RNE
    return (unsigned short)r;
}

__device__ __forceinline__ float bclo(unsigned d) {       // low bf16 -> f32
    return __builtin_bit_cast(float, d << 16);
}
__device__ __forceinline__ float bchi(unsigned d) {       // high bf16 -> f32
    return __builtin_bit_cast(float, d & 0xffff0000u);
}

// x: (B, C, N) fp32 -> xt: (B, N, C) bf16.  Also (16 blocks of y==0) W fp32 -> Wbf bf16.
__global__ __launch_bounds__(256) void transpose_kernel(
        const float* __restrict__ x, unsigned short* __restrict__ xt,
        const float* __restrict__ W, unsigned short* __restrict__ Wbf) {
    __shared__ float tile[64][65];
    const int b  = blockIdx.y;
    const int n0 = blockIdx.x * 64;
    const int t  = threadIdx.x;
    const int ln = t & 63;
    const int r  = t >> 6;

    const float* xb = x + (size_t)b * CC * NN;
    #pragma unroll
    for (int s = 0; s < 64; s += 4) {
        int c = s + r;
        tile[c][ln] = xb[(size_t)c * NN + n0 + ln];
    }
    __syncthreads();
    unsigned short* xtb = xt + ((size_t)b * NN + n0) * CC;
    #pragma unroll
    for (int s = 0; s < 64; s += 4) {
        int n = s + r;
        xtb[n * CC + ln] = f2b(tile[ln][n]);
    }

    if (b == 0 && blockIdx.x < 16) {
        int idx = blockIdx.x * 1024 + t * 4;
        float4 v = *reinterpret_cast<const float4*>(W + idx);
        ushort4 o;
        o.x = f2b(v.x); o.y = f2b(v.y); o.z = f2b(v.z); o.w = f2b(v.w);
        *reinterpret_cast<ushort4*>(Wbf + idx) = o;
    }
}

// xt: (B,N,64) bf16; Wbf: (128,128) bf16; eidx: (2,B,N,16); bias: (128); out: (B,128,N) fp32
__global__ __launch_bounds__(256) void main_kernel(
        const unsigned short* __restrict__ xt,
        const unsigned short* __restrict__ Wbf,
        const int*            __restrict__ eidx,
        const float*          __restrict__ bias,
        float*                __restrict__ out) {
    __shared__ unsigned short Wl[128 * SW];
    __shared__ unsigned short hl[64 * SH];
    __shared__ int eL[2048];                  // [0..1023]=e0 slab, [1024..2047]=e1 slab

    const int t    = threadIdx.x;
    const int lane = t & 63;
    const int w    = t >> 6;
    const int b    = blockIdx.y;
    const int n_base = blockIdx.x * 64;

    // ---- stage indices (coalesced) ----
    const int* e0 = eidx + ((size_t)b * NN + n_base) * KK;
    const int* e1 = e0 + (size_t)BB * NN * KK;
    *reinterpret_cast<int4*>(&eL[t * 4])        = *reinterpret_cast<const int4*>(e0 + t * 4);
    *reinterpret_cast<int4*>(&eL[1024 + t * 4]) = *reinterpret_cast<const int4*>(e1 + t * 4);

    // ---- stage W (bf16 global -> LDS, padded rows) ----
    #pragma unroll
    for (int it = 0; it < 8; it++) {
        int flat = it * 2048 + t * 8;
        int row = flat >> 7, col = flat & 127;
        *reinterpret_cast<int4*>(&Wl[row * SW + col]) =
            *reinterpret_cast<const int4*>(Wbf + flat);
    }
    __syncthreads();

    // ---- phase 1: gather + max, 8 lanes per node row, 2 batches of 8 nodes/wave ----
    const unsigned short* xtb = xt + (size_t)b * NN * CC;
    const int g = lane >> 3;     // node within batch
    const int p = lane & 7;      // 16B chunk within row (channels p*8 .. p*8+7)

    #pragma unroll
    for (int bt = 0; bt < 2; bt++) {
        const int nl = w * 16 + bt * 8 + g;
        uint4 xr = *reinterpret_cast<const uint4*>(xtb + (size_t)(n_base + nl) * CC + p * 8);

        float m[8];
        #pragma unroll
        for (int j = 0; j < 8; j++) m[j] = -1e30f;

        #pragma unroll
        for (int k = 0; k < KK; k++) {
            int ij = eL[nl * KK + k];            // broadcast within group
            int ii = eL[1024 + nl * KK + k];
            uint4 xj = *reinterpret_cast<const uint4*>(xtb + (size_t)ij * CC + p * 8);
            uint4 xi = *reinterpret_cast<const uint4*>(xtb + (size_t)ii * CC + p * 8);
            m[0] = fmaxf(m[0], bclo(xj.x) - bclo(xi.x));
            m[1] = fmaxf(m[1], bchi(xj.x) - bchi(xi.x));
            m[2] = fmaxf(m[2], bclo(xj.y) - bclo(xi.y));
            m[3] = fmaxf(m[3], bchi(xj.y) - bchi(xi.y));
            m[4] = fmaxf(m[4], bclo(xj.z) - bclo(xi.z));
            m[5] = fmaxf(m[5], bchi(xj.z) - bchi(xi.z));
            m[6] = fmaxf(m[6], bclo(xj.w) - bclo(xi.w));
            m[7] = fmaxf(m[7], bchi(xj.w) - bchi(xi.w));
        }

        // pack h[nl][2c]=x[c], h[nl][2c+1]=m[c] for c = p*8 .. p*8+7  (32B per lane)
        unsigned xs[8];
        xs[0] = xr.x & 0xffffu; xs[1] = xr.x >> 16;
        xs[2] = xr.y & 0xffffu; xs[3] = xr.y >> 16;
        xs[4] = xr.z & 0xffffu; xs[5] = xr.z >> 16;
        xs[6] = xr.w & 0xffffu; xs[7] = xr.w >> 16;
        unsigned od[8];
        #pragma unroll
        for (int j = 0; j < 8; j++)
            od[j] = xs[j] | ((unsigned)f2b(m[j]) << 16);

        unsigned short* dst = &hl[nl * SH + p * 16];
        uint4 lo, hi;
        lo.x = od[0]; lo.y = od[1]; lo.z = od[2]; lo.w = od[3];
        hi.x = od[4]; hi.y = od[5]; hi.z = od[6]; hi.w = od[7];
        *reinterpret_cast<uint4*>(dst)     = lo;
        *reinterpret_cast<uint4*>(dst + 8) = hi;
    }
    __syncthreads();

    // ---- phase 2: out[128 x 64] = W[128x128] @ h[128x64], MFMA bf16 ----
    const int quad = lane >> 4;
    const int l15  = lane & 15;
    const int o0w  = w * 32;

    bf16x8 afr[2][4];
    #pragma unroll
    for (int ot = 0; ot < 2; ot++)
        #pragma unroll
        for (int ks = 0; ks < 4; ks++) {
            const unsigned short* ap = &Wl[(o0w + ot * 16 + l15) * SW + ks * 32 + quad * 8];
            afr[ot][ks] = *reinterpret_cast<const bf16x8*>(ap);
        }

    #pragma unroll
    for (int nt = 0; nt < 4; nt++) {
        f32x4 acc0 = {0.f, 0.f, 0.f, 0.f};
        f32x4 acc1 = {0.f, 0.f, 0.f, 0.f};
        #pragma unroll
        for (int ks = 0; ks < 4; ks++) {
            const unsigned short* bp = &hl[(nt * 16 + l15) * SH + ks * 32 + quad * 8];
            bf16x8 bfr = *reinterpret_cast<const bf16x8*>(bp);
            acc0 = __builtin_amdgcn_mfma_f32_16x16x32_bf16(afr[0][ks], bfr, acc0, 0, 0, 0);
            acc1 = __builtin_amdgcn_mfma_f32_16x16x32_bf16(afr[1][ks], bfr, acc1, 0, 0, 0);
        }
        int n_g = n_base + nt * 16 + l15;
        #pragma unroll
        for (int r = 0; r < 4; r++) {
            int o_a = o0w + quad * 4 + r;
            int o_b = o0w + 16 + quad * 4 + r;
            float va = acc0[r] + bias[o_a];
            float vb = acc1[r] + bias[o_b];
            out[((size_t)b * OO + o_a) * NN + n_g] = fmaxf(va, 0.f);
            out[((size_t)b * OO + o_b) * NN + n_g] = fmaxf(vb, 0.f);
        }
    }
}

extern "C" void kernel_launch(void* const* d_in, const int* in_sizes, int n_in,
                              void* d_out, int out_size, void* d_ws, size_t ws_size,
                              hipStream_t stream) {
    const float* x    = (const float*)d_in[0];
    const int*   eidx = (const int*)d_in[1];
    const float* W    = (const float*)d_in[2];
    const float* bias = (const float*)d_in[3];
    float* out = (float*)d_out;

    unsigned short* xt  = (unsigned short*)d_ws;                           // 4 MB
    unsigned short* Wbf = (unsigned short*)((char*)d_ws + 4 * 1024 * 1024); // 32 KB

    dim3 blk(256);
    dim3 grid(NN / 64, BB);
    transpose_kernel<<<grid, blk, 0, stream>>>(x, xt, W, Wbf);
    main_kernel<<<grid, blk, 0, stream>>>(xt, Wbf, eidx, bias, out);
}